// Round 1
// baseline (24236.641 us; speedup 1.0000x reference)
//
#include <hip/hip_runtime.h>
#include <cstdint>

#define BB 32     // batch
#define TT 1024   // seq len
#define II 512    // input dim
#define HH 1024   // hidden dim
#define NTHREADS 512
#define NBLOCKS  256  // 1024 units / 4 per block

__device__ __forceinline__ float sigm(float v) { return 1.0f / (1.0f + __expf(-v)); }
__device__ __forceinline__ float mytanh(float v) {
  float e = __expf(2.0f * v);
  return (e - 1.0f) / (e + 1.0f);
}

// One timestep: gates = [x_t, h] @ W^T + b ; LSTM cell update.
// Block owns 4 hidden units (16 W rows in registers, k strided across 64 lanes).
// Wave w: unit = blockIdx.x*4 + (w>>1), batches (w&1)*16 .. +15.
__global__ __launch_bounds__(NTHREADS, 2)
void lstm_step(const float* __restrict__ x, const float* __restrict__ W,
               const float* __restrict__ bias, const float* __restrict__ h_in,
               float* __restrict__ h_out, float* __restrict__ c_state,
               float* __restrict__ out, int t)
{
  __shared__ __align__(16) float sm[BB * HH];  // 128 KB; holds x_t (first 64KB) then h
  const int tid   = threadIdx.x;
  const int wave  = tid >> 6;
  const int lane  = tid & 63;
  const int ul    = wave >> 1;            // unit within block, 0..3
  const int u     = blockIdx.x * 4 + ul;  // global hidden unit
  const int bbase = (wave & 1) * 16;

  // --- W rows for this unit's 4 gates, lane-strided by 64 over 1536 cols ---
  float wreg[4][24];
  float bias4[4];
  #pragma unroll
  for (int q = 0; q < 4; ++q) {
    const float* wr = W + (size_t)(q * HH + u) * (II + HH);
    #pragma unroll
    for (int j = 0; j < 24; ++j) wreg[q][j] = wr[lane + 64 * j];
    bias4[q] = bias[q * HH + u];
  }

  float acc[16][4];
  #pragma unroll
  for (int bl = 0; bl < 16; ++bl)
    #pragma unroll
    for (int q = 0; q < 4; ++q) acc[bl][q] = 0.0f;

  // --- stage x_t into LDS: [b][i] 32x512 ---
  for (int idx = tid; idx < BB * II / 4; idx += NTHREADS) {
    const int b  = idx >> 7;       // idx / 128
    const int ii = idx & 127;
    reinterpret_cast<float4*>(sm)[idx] =
        reinterpret_cast<const float4*>(x + (size_t)b * TT * II + (size_t)t * II)[ii];
  }
  __syncthreads();

  // x-part of the dot (k = 0..511)
  #pragma unroll
  for (int bl = 0; bl < 16; ++bl) {
    const float* row = sm + (bbase + bl) * II;
    float xv[8];
    #pragma unroll
    for (int j = 0; j < 8; ++j) xv[j] = row[lane + 64 * j];
    #pragma unroll
    for (int q = 0; q < 4; ++q)
      #pragma unroll
      for (int j = 0; j < 8; ++j) acc[bl][q] = fmaf(xv[j], wreg[q][j], acc[bl][q]);
  }
  __syncthreads();

  // --- stage h into LDS: [b][k] 32x1024 (linear copy, conflict-free) ---
  for (int idx = tid; idx < BB * HH / 4; idx += NTHREADS)
    reinterpret_cast<float4*>(sm)[idx] = reinterpret_cast<const float4*>(h_in)[idx];
  __syncthreads();

  // h-part of the dot (k = 0..1023) -> W cols 512..1535 = wreg[q][8..23]
  #pragma unroll
  for (int bl = 0; bl < 16; ++bl) {
    const float* row = sm + (bbase + bl) * HH;
    float hv[16];
    #pragma unroll
    for (int j = 0; j < 16; ++j) hv[j] = row[lane + 64 * j];
    #pragma unroll
    for (int q = 0; q < 4; ++q)
      #pragma unroll
      for (int j = 0; j < 16; ++j) acc[bl][q] = fmaf(hv[j], wreg[q][8 + j], acc[bl][q]);
  }

  // --- butterfly reduce over 64 lanes; lane bl keeps batch bbase+bl ---
  float g4[4] = {0.f, 0.f, 0.f, 0.f};
  #pragma unroll
  for (int bl = 0; bl < 16; ++bl) {
    float a0 = acc[bl][0], a1 = acc[bl][1], a2 = acc[bl][2], a3 = acc[bl][3];
    #pragma unroll
    for (int off = 32; off; off >>= 1) {
      a0 += __shfl_xor(a0, off, 64);
      a1 += __shfl_xor(a1, off, 64);
      a2 += __shfl_xor(a2, off, 64);
      a3 += __shfl_xor(a3, off, 64);
    }
    if (lane == bl) { g4[0] = a0; g4[1] = a1; g4[2] = a2; g4[3] = a3; }
  }

  // --- cell update (lanes 0..15 hold batches bbase+lane) ---
  if (lane < 16) {
    const int b = bbase + lane;
    const float gi = sigm(g4[0] + bias4[0]);
    const float gf = sigm(g4[1] + bias4[1]);
    const float gg = mytanh(g4[2] + bias4[2]);
    const float go = sigm(g4[3] + bias4[3]);
    const int ci = b * HH + u;
    const float cn = gf * c_state[ci] + gi * gg;
    c_state[ci] = cn;
    const float hn = go * mytanh(cn);
    h_out[ci] = hn;
    out[(size_t)b * TT * HH + (size_t)t * HH + u] = hn;
  }
}

extern "C" void kernel_launch(void* const* d_in, const int* in_sizes, int n_in,
                              void* d_out, int out_size, void* d_ws, size_t ws_size,
                              hipStream_t stream)
{
  const float* x = (const float*)d_in[0];
  const float* W = (const float*)d_in[1];
  const float* b = (const float*)d_in[2];
  float* out = (float*)d_out;

  float* h0 = (float*)d_ws;        // 32x1024
  float* h1 = h0 + BB * HH;        // 32x1024
  float* c  = h1 + BB * HH;        // 32x1024
  hipMemsetAsync(d_ws, 0, (size_t)3 * BB * HH * sizeof(float), stream);

  for (int t = 0; t < TT; ++t) {
    const float* hin = (t & 1) ? h1 : h0;
    float*      hout = (t & 1) ? h0 : h1;
    lstm_step<<<NBLOCKS, NTHREADS, 0, stream>>>(x, W, b, hin, hout, c, out, t);
  }
}